// Round 7
// baseline (93.068 us; speedup 1.0000x reference)
//
#include <hip/hip_runtime.h>

// DualPathFusion: B=2, C=32, D=32, H=128, W=128, f32.
// out[b,c,s] = f1*g1 + f2*g2, g = 2-way softmax of per-channel linear combos
// (avg term folded into coefficients).
//
// R7: occupancy-first structure. Each QUAD of lanes co-owns 2 spatial
// positions; each lane handles 8 of the 32 channels (16 bf16-packed stash
// VGPRs instead of 64). Partial logits quad-reduced via 2x __shfl_xor
// (in-register, no barrier). Per-channel coeffs staged once per block in a
// 512B LDS table, transposed so quad reads are conflict-free. f32x2 loads:
// same-cb lanes are spatially consecutive -> every instruction touches 8
// fully-utilized 64B lines. Target: ~8 waves/SIMD vs R5's 5 (R6 lesson:
// occupancy dominates load width here). No min-waves hint (R4: spill).

#define CCH 32
#define LOG2_SPATIAL 19          // D*H*W = 32*128*128 = 2^19
#define SPATIAL (1u << LOG2_SPATIAL)

typedef float f32x2 __attribute__((ext_vector_type(2)));
typedef float f32x4 __attribute__((ext_vector_type(4)));

// two f32 -> packed 2x bf16 (round-to-nearest-even), pure bit ops.
__device__ __forceinline__ unsigned pack_bf16x2(float x, float y) {
    unsigned bx = __float_as_uint(x);
    unsigned by = __float_as_uint(y);
    bx = (bx + 0x7FFFu + ((bx >> 16) & 1u)) >> 16;
    by = (by + 0x7FFFu + ((by >> 16) & 1u)) >> 16;
    return bx | (by << 16);
}

__device__ __forceinline__ f32x2 unpack_bf16x2(unsigned h) {
    f32x2 v;
    v.x = __uint_as_float(h << 16);
    v.y = __uint_as_float(h & 0xFFFF0000u);
    return v;
}

__global__ __launch_bounds__(256) void dual_path_fusion_kernel(
    const float* __restrict__ f1, const float* __restrict__ f2,
    const float* __restrict__ w1, const float* __restrict__ b1,
    const float* __restrict__ w2, const float* __restrict__ b2,
    float* __restrict__ out)
{
    // --- per-block coefficient table: entry (i*4+cb) = {c1,h1,c2,h2} of
    //     channel c = cb*8+i. Transposed layout -> quad LDS reads hit 4
    //     different bank groups (conflict-free).
    __shared__ f32x4 coeff[CCH];
    unsigned tid = threadIdx.x;
    if (tid < CCH) {
        unsigned c = tid;
        float h1 = 0.5f * w1[CCH + c];
        float h2 = 0.5f * w2[CCH + c];
        f32x4 e;
        e.x = w1[c] + h1;  e.y = h1;
        e.z = w2[c] + h2;  e.w = h2;
        coeff[((c & 7u) << 2) | (c >> 3)] = e;
    }
    __syncthreads();

    unsigned t    = blockIdx.x * 256u + tid;
    unsigned quad = t >> 2;                  // which position-pair
    unsigned cb   = t & 3u;                  // which channel-block (8 ch)
    unsigned p    = quad << 1;               // first of 2 consecutive positions
    unsigned bb   = p >> LOG2_SPATIAL;       // batch (pairs never straddle)
    unsigned r    = p & (SPATIAL - 1u);
    // element offset of (batch bb, channel cb*8, position r):
    unsigned base = (bb << (LOG2_SPATIAL + 5)) + (cb << 22) + r;

    unsigned h1s[8], h2s[8];                 // bf16-packed stash: 16 VGPRs
    float a1x = 0.f, a1y = 0.f, a2x = 0.f, a2y = 0.f;

#pragma unroll
    for (int i = 0; i < 8; ++i) {
        f32x2 v1 = *(const f32x2*)(f1 + base + ((unsigned)i << LOG2_SPATIAL));
        f32x2 v2 = *(const f32x2*)(f2 + base + ((unsigned)i << LOG2_SPATIAL));
        f32x4 cf = coeff[(i << 2) | cb];     // {c1,h1,c2,h2} for channel cb*8+i
        a1x = fmaf(v1.x, cf.x, fmaf(v2.x, cf.y, a1x));
        a1y = fmaf(v1.y, cf.x, fmaf(v2.y, cf.y, a1y));
        a2x = fmaf(v2.x, cf.z, fmaf(v1.x, cf.w, a2x));
        a2y = fmaf(v2.y, cf.z, fmaf(v1.y, cf.w, a2y));
        h1s[i] = pack_bf16x2(v1.x, v1.y);
        h2s[i] = pack_bf16x2(v2.x, v2.y);
    }

    // quad-reduce partial logits (lanes 4k..4k+3 share a position-pair)
    a1x += __shfl_xor(a1x, 1); a1x += __shfl_xor(a1x, 2);
    a1y += __shfl_xor(a1y, 1); a1y += __shfl_xor(a1y, 2);
    a2x += __shfl_xor(a2x, 1); a2x += __shfl_xor(a2x, 2);
    a2y += __shfl_xor(a2y, 1); a2y += __shfl_xor(a2y, 2);

    // 2-way softmax per position (redundant across the quad -- cheap)
    float ex  = __expf((a2x + b2[0]) - (a1x + b1[0]));
    float ey  = __expf((a2y + b2[0]) - (a1y + b1[0]));
    float g1x = 1.0f / (1.0f + ex), g2x = 1.0f - g1x;
    float g1y = 1.0f / (1.0f + ey), g2y = 1.0f - g1y;

#pragma unroll
    for (int i = 0; i < 8; ++i) {
        f32x2 v1 = unpack_bf16x2(h1s[i]);
        f32x2 v2 = unpack_bf16x2(h2s[i]);
        f32x2 o;
        o.x = fmaf(v1.x, g1x, v2.x * g2x);
        o.y = fmaf(v1.y, g1y, v2.y * g2y);
        __builtin_nontemporal_store(o, (f32x2*)(out + base + ((unsigned)i << LOG2_SPATIAL)));
    }
}

extern "C" void kernel_launch(void* const* d_in, const int* in_sizes, int n_in,
                              void* d_out, int out_size, void* d_ws, size_t ws_size,
                              hipStream_t stream) {
    const float* f1 = (const float*)d_in[0];
    const float* f2 = (const float*)d_in[1];
    const float* w1 = (const float*)d_in[2];
    const float* b1 = (const float*)d_in[3];
    const float* w2 = (const float*)d_in[4];
    const float* b2 = (const float*)d_in[5];
    float* out = (float*)d_out;

    unsigned total   = (unsigned)(in_sizes[0] / CCH); // B*D*H*W = 1,048,576 positions
    unsigned nthread = (total >> 1) << 2;             // 4 lanes per position-pair = 2,097,152
    unsigned block   = 256;
    unsigned grid    = nthread / block;               // 8192 (exact)
    dual_path_fusion_kernel<<<grid, block, 0, stream>>>(f1, f2, w1, b1, w2, b2, out);
}

// Round 8
// 91.198 us; speedup vs baseline: 1.0205x; 1.0205x over previous
//
#include <hip/hip_runtime.h>

// DualPathFusion: B=2, C=32, D=32, H=128, W=128, f32.
// out[b,c,s] = f1*g1 + f2*g2, g = 2-way softmax of per-channel linear combos
// (avg term folded into coefficients).
//
// R8: balanced occupancy x forced-MLP structure.
//  - 2-lane split: lane parity picks a 16-channel half; logits combined with
//    one __shfl_xor(.,1). Stash = 64 f32 VGPRs -> ~85 total -> 6 waves/SIMD.
//  - LOAD-ALL-FIRST: all 32 global loads issue into live arrays before any
//    use, so the allocator cannot recycle destinations (R7 failure mode:
//    interleaved loop let it serialize at 32 VGPRs). 32 loads in flight
//    per thread, guaranteed.
//  - f32 stash (no bf16 rounding), LDS coeff table, nontemporal stores,
//    no min-waves hint (R4: causes spill).

#define CCH 32
#define LOG2_SPATIAL 19          // D*H*W = 32*128*128 = 2^19
#define SPATIAL (1u << LOG2_SPATIAL)

typedef float f32x2 __attribute__((ext_vector_type(2)));
typedef float f32x4 __attribute__((ext_vector_type(4)));

__global__ __launch_bounds__(256) void dual_path_fusion_kernel(
    const float* __restrict__ f1, const float* __restrict__ f2,
    const float* __restrict__ w1, const float* __restrict__ b1,
    const float* __restrict__ w2, const float* __restrict__ b2,
    float* __restrict__ out)
{
    // Per-block coefficient table: coeff[c] = {w1[c]+.5*w1[C+c], .5*w1[C+c],
    //                                          w2[c]+.5*w2[C+c], .5*w2[C+c]}
    __shared__ f32x4 coeff[CCH];
    unsigned tid = threadIdx.x;
    if (tid < CCH) {
        float h1 = 0.5f * w1[CCH + tid];
        float h2 = 0.5f * w2[CCH + tid];
        f32x4 e;
        e.x = w1[tid] + h1;  e.y = h1;
        e.z = w2[tid] + h2;  e.w = h2;
        coeff[tid] = e;
    }
    __syncthreads();

    unsigned t    = blockIdx.x * 256u + tid;
    unsigned half = t & 1u;                  // which 16-channel half
    unsigned q    = t >> 1;                  // position-pair index
    unsigned p    = q << 1;                  // first of 2 consecutive positions
    unsigned bb   = p >> LOG2_SPATIAL;       // batch (pairs never straddle)
    unsigned r    = p & (SPATIAL - 1u);
    unsigned cb   = half << 4;               // starting channel (0 or 16)
    unsigned base = (bb << (LOG2_SPATIAL + 5)) + (cb << LOG2_SPATIAL) + r;

    // ---- load-all-first: 32 loads in flight, live until the store loop ----
    f32x2 v1[16], v2[16];                    // 64 f32 VGPRs
#pragma unroll
    for (int i = 0; i < 16; ++i) {
        v1[i] = *(const f32x2*)(f1 + base + ((unsigned)i << LOG2_SPATIAL));
        v2[i] = *(const f32x2*)(f2 + base + ((unsigned)i << LOG2_SPATIAL));
    }

    // ---- partial logits over this lane's 16 channels (f32, full precision)
    float a1x = 0.f, a1y = 0.f, a2x = 0.f, a2y = 0.f;
#pragma unroll
    for (int i = 0; i < 16; ++i) {
        f32x4 cf = coeff[cb + i];
        a1x = fmaf(v1[i].x, cf.x, fmaf(v2[i].x, cf.y, a1x));
        a1y = fmaf(v1[i].y, cf.x, fmaf(v2[i].y, cf.y, a1y));
        a2x = fmaf(v2[i].x, cf.z, fmaf(v1[i].x, cf.w, a2x));
        a2y = fmaf(v2[i].y, cf.z, fmaf(v1[i].y, cf.w, a2y));
    }

    // ---- combine halves (partner lane = lane^1), softmax ----
    a1x += __shfl_xor(a1x, 1);
    a1y += __shfl_xor(a1y, 1);
    a2x += __shfl_xor(a2x, 1);
    a2y += __shfl_xor(a2y, 1);

    float ex  = __expf((a2x + b2[0]) - (a1x + b1[0]));
    float ey  = __expf((a2y + b2[0]) - (a1y + b1[0]));
    float g1x = 1.0f / (1.0f + ex), g2x = 1.0f - g1x;
    float g1y = 1.0f / (1.0f + ey), g2y = 1.0f - g1y;

    // ---- blend + store this lane's 16 channels ----
#pragma unroll
    for (int i = 0; i < 16; ++i) {
        f32x2 o;
        o.x = fmaf(v1[i].x, g1x, v2[i].x * g2x);
        o.y = fmaf(v1[i].y, g1y, v2[i].y * g2y);
        __builtin_nontemporal_store(o, (f32x2*)(out + base + ((unsigned)i << LOG2_SPATIAL)));
    }
}

extern "C" void kernel_launch(void* const* d_in, const int* in_sizes, int n_in,
                              void* d_out, int out_size, void* d_ws, size_t ws_size,
                              hipStream_t stream) {
    const float* f1 = (const float*)d_in[0];
    const float* f2 = (const float*)d_in[1];
    const float* w1 = (const float*)d_in[2];
    const float* b1 = (const float*)d_in[3];
    const float* w2 = (const float*)d_in[4];
    const float* b2 = (const float*)d_in[5];
    float* out = (float*)d_out;

    unsigned total   = (unsigned)(in_sizes[0] / CCH); // B*D*H*W = 1,048,576 positions
    unsigned nthread = total;                         // 2 lanes x 2 positions each
    unsigned block   = 256;
    unsigned grid    = nthread / block;               // 4096 (exact)
    dual_path_fusion_kernel<<<grid, block, 0, stream>>>(f1, f2, w1, b1, w2, b2, out);
}

// Round 9
// 61.733 us; speedup vs baseline: 1.5076x; 1.4773x over previous
//
#include <hip/hip_runtime.h>

// DualPathFusion: B=2, C=32, D=32, H=128, W=128, f32.
// out[b,c,s] = f1*g1 + f2*g2, g = 2-way softmax of per-channel linear combos
// (avg term folded into coefficients).
//
// R9: R5's proven hold-structure (interleaved load->fma->PACK; the pack makes
// remat costlier than holding, so the allocator keeps the stash) with:
//  - f32x4 loads (16 B/lane, the width of the 6.29 TB/s m13 ceiling),
//  - 4 positions x 16 channels per lane (2-lane split, one __shfl_xor(1)
//    per accumulator to combine halves) -> stash is 64 u32, VGPR ~110,
//  - LDS coeff table (512 B, even/odd lanes read 2 addresses -> broadcast),
//  - nontemporal stores, no min-waves hint (R4: spill).
// Per load instruction: even lanes cover 512 B of plane ch, odd lanes 512 B
// of plane ch+16 — two contiguous runs, fully-utilized 64 B lines.

#define CCH 32
#define LOG2_SPATIAL 19          // D*H*W = 32*128*128 = 2^19
#define SPATIAL (1u << LOG2_SPATIAL)

typedef float f32x2 __attribute__((ext_vector_type(2)));
typedef float f32x4 __attribute__((ext_vector_type(4)));

// two f32 -> packed 2x bf16 (round-to-nearest-even), pure bit ops.
__device__ __forceinline__ unsigned pack_bf16x2(float x, float y) {
    unsigned bx = __float_as_uint(x);
    unsigned by = __float_as_uint(y);
    bx = (bx + 0x7FFFu + ((bx >> 16) & 1u)) >> 16;
    by = (by + 0x7FFFu + ((by >> 16) & 1u)) >> 16;
    return bx | (by << 16);
}

__device__ __forceinline__ f32x2 unpack_bf16x2(unsigned h) {
    f32x2 v;
    v.x = __uint_as_float(h << 16);
    v.y = __uint_as_float(h & 0xFFFF0000u);
    return v;
}

__global__ __launch_bounds__(256) void dual_path_fusion_kernel(
    const float* __restrict__ f1, const float* __restrict__ f2,
    const float* __restrict__ w1, const float* __restrict__ b1,
    const float* __restrict__ w2, const float* __restrict__ b2,
    float* __restrict__ out)
{
    // coeff[c] = {w1[c]+.5*w1[C+c], .5*w1[C+c], w2[c]+.5*w2[C+c], .5*w2[C+c]}
    __shared__ f32x4 coeff[CCH];
    unsigned tid = threadIdx.x;
    if (tid < CCH) {
        float h1 = 0.5f * w1[CCH + tid];
        float h2 = 0.5f * w2[CCH + tid];
        f32x4 e;
        e.x = w1[tid] + h1;  e.y = h1;
        e.z = w2[tid] + h2;  e.w = h2;
        coeff[tid] = e;
    }
    __syncthreads();

    unsigned t    = blockIdx.x * 256u + tid;
    unsigned half = t & 1u;                  // 16-channel half (0 or 1)
    unsigned q    = t >> 1;                  // position-quad index
    unsigned p    = q << 2;                  // first of 4 consecutive positions
    unsigned bb   = p >> LOG2_SPATIAL;       // batch (quads never straddle)
    unsigned r    = p & (SPATIAL - 1u);
    unsigned chb  = half << 4;               // starting channel (0 or 16)
    unsigned base = (bb << (LOG2_SPATIAL + 5)) + (half << 23) + r;

    unsigned h1s[16][2], h2s[16][2];         // bf16-packed stash: 64 VGPRs
    float a1[4] = {0.f, 0.f, 0.f, 0.f};
    float a2[4] = {0.f, 0.f, 0.f, 0.f};

#pragma unroll
    for (int i = 0; i < 16; ++i) {
        f32x4 v1 = *(const f32x4*)(f1 + base + ((unsigned)i << LOG2_SPATIAL));
        f32x4 v2 = *(const f32x4*)(f2 + base + ((unsigned)i << LOG2_SPATIAL));
        f32x4 cf = coeff[chb + i];           // 2 addresses/wave -> broadcast
#pragma unroll
        for (int k = 0; k < 4; ++k) {
            a1[k] = fmaf(v1[k], cf.x, fmaf(v2[k], cf.y, a1[k]));
            a2[k] = fmaf(v2[k], cf.z, fmaf(v1[k], cf.w, a2[k]));
        }
        h1s[i][0] = pack_bf16x2(v1.x, v1.y);
        h1s[i][1] = pack_bf16x2(v1.z, v1.w);
        h2s[i][0] = pack_bf16x2(v2.x, v2.y);
        h2s[i][1] = pack_bf16x2(v2.z, v2.w);
    }

    // combine channel halves (partner lane), add biases, 2-way softmax
    float g1[4], g2[4];
    float bb1 = b1[0], bb2 = b2[0];
#pragma unroll
    for (int k = 0; k < 4; ++k) {
        float s1 = a1[k] + __shfl_xor(a1[k], 1);
        float s2 = a2[k] + __shfl_xor(a2[k], 1);
        float e  = __expf((s2 + bb2) - (s1 + bb1));
        g1[k] = 1.0f / (1.0f + e);
        g2[k] = 1.0f - g1[k];
    }

#pragma unroll
    for (int i = 0; i < 16; ++i) {
        f32x2 lo1 = unpack_bf16x2(h1s[i][0]), hi1 = unpack_bf16x2(h1s[i][1]);
        f32x2 lo2 = unpack_bf16x2(h2s[i][0]), hi2 = unpack_bf16x2(h2s[i][1]);
        f32x4 o;
        o.x = fmaf(lo1.x, g1[0], lo2.x * g2[0]);
        o.y = fmaf(lo1.y, g1[1], lo2.y * g2[1]);
        o.z = fmaf(hi1.x, g1[2], hi2.x * g2[2]);
        o.w = fmaf(hi1.y, g1[3], hi2.y * g2[3]);
        __builtin_nontemporal_store(o, (f32x4*)(out + base + ((unsigned)i << LOG2_SPATIAL)));
    }
}

extern "C" void kernel_launch(void* const* d_in, const int* in_sizes, int n_in,
                              void* d_out, int out_size, void* d_ws, size_t ws_size,
                              hipStream_t stream) {
    const float* f1 = (const float*)d_in[0];
    const float* f2 = (const float*)d_in[1];
    const float* w1 = (const float*)d_in[2];
    const float* b1 = (const float*)d_in[3];
    const float* w2 = (const float*)d_in[4];
    const float* b2 = (const float*)d_in[5];
    float* out = (float*)d_out;

    unsigned total   = (unsigned)(in_sizes[0] / CCH); // B*D*H*W = 1,048,576 positions
    unsigned nthread = total >> 1;                    // 4 pos x 2 lanes -> 524,288
    unsigned block   = 256;
    unsigned grid    = nthread / block;               // 2048 (exact)
    dual_path_fusion_kernel<<<grid, block, 0, stream>>>(f1, f2, w1, b1, w2, b2, out);
}